// Round 2
// baseline (6229.380 us; speedup 1.0000x reference)
//
#include <hip/hip_runtime.h>

#define NF 481
#define NT 500
#define NDELTA 4
#define CH 16
#define HID 32
#define NB 16
#define NSEQ (NB*NF)   // 7696

// conv tiling
#define FT 16          // f-tile (outputs per block)
#define TT 32          // t-tile
#define TS 36          // padded t-stride in floats (144 B: 16B-aligned, rotates banks)

__device__ __forceinline__ float sig_(float v) { return 1.0f / (1.0f + __expf(-v)); }

// -------------------------------------------------------------------------
// Kernel 1: fused conv1(4->16,k=9,pad4)+PReLU -> conv2(16->16,k=5,pad2)+PReLU
// features: (B, 4, F, T)  ->  x: (N=B*F, T, 16)
// Block: (b, f0=blockIdx.y*FT), 256 threads, loops over t in chunks of TT.
// -------------------------------------------------------------------------
__global__ __launch_bounds__(256) void conv_kernel(
    const float* __restrict__ feat,
    const float* __restrict__ w1, const float* __restrict__ b1, const float* __restrict__ a1p,
    const float* __restrict__ w2, const float* __restrict__ b2, const float* __restrict__ a2p,
    float* __restrict__ xout)
{
    __shared__ float s_feat[NDELTA*28*TS];   // f-halo 28 = FT + 2*(4+2)
    __shared__ float s_y1[CH*20*TS];         // f-halo 20 = FT + 2*2
    __shared__ float s_w1[CH*NDELTA*9];
    __shared__ float s_w2[CH*CH*5];
    __shared__ float s_b1[CH], s_b2[CH];

    const int b   = blockIdx.x;
    const int f0  = blockIdx.y * FT;
    const int tid = threadIdx.x;
    const float a1 = a1p[0], a2 = a2p[0];

    for (int i = tid; i < CH*NDELTA*9; i += 256) s_w1[i] = w1[i];
    for (int i = tid; i < CH*CH*5;     i += 256) s_w2[i] = w2[i];
    if (tid < CH) { s_b1[tid] = b1[tid]; s_b2[tid] = b2[tid]; }

    for (int t0 = 0; t0 < NT; t0 += TT) {
        __syncthreads();   // previous iteration fully consumed (also covers weight staging)

        // ---- stage feature tile (zero-padded in f and t) ----
        {
            const int lane = tid & 31;
            for (int r = (tid >> 5); r < NDELTA*28; r += 8) {
                const int d = r / 28, ffp = r % 28;
                const int gf = f0 - 6 + ffp;
                const int gt = t0 + lane;
                float v = 0.0f;
                if (gf >= 0 && gf < NF && gt < NT)
                    v = feat[((size_t)(b*NDELTA + d)*NF + gf)*NT + gt];
                s_feat[(d*28 + ffp)*TS + lane] = v;
            }
        }
        __syncthreads();

        // ---- conv1 + PReLU -> s_y1 (zero outside valid f: conv2's zero pad) ----
        for (int p = tid; p < CH*20; p += 256) {
            const int c = p / 20, fp = p % 20;
            const int gf1 = f0 - 2 + fp;        // global f of this y1 column
            float acc[TT];
            const float bb = s_b1[c];
            #pragma unroll
            for (int t = 0; t < TT; t++) acc[t] = bb;
            #pragma unroll
            for (int d = 0; d < NDELTA; d++) {
                #pragma unroll
                for (int k = 0; k < 9; k++) {
                    const float w = s_w1[(c*NDELTA + d)*9 + k];
                    const float* src = &s_feat[(d*28 + fp + k)*TS];
                    #pragma unroll
                    for (int t = 0; t < TT; t++) acc[t] = fmaf(w, src[t], acc[t]);
                }
            }
            float* dst = &s_y1[(c*20 + fp)*TS];
            const bool valid = (gf1 >= 0 && gf1 < NF);
            #pragma unroll
            for (int t = 0; t < TT; t++) {
                float v = acc[t];
                v = (v >= 0.0f) ? v : a1*v;
                dst[t] = valid ? v : 0.0f;
            }
        }
        __syncthreads();

        // ---- conv2 + PReLU -> global x (N, T, 16) ----
        {
            const int c = tid >> 4, f = tid & 15;
            const int gf = f0 + f;
            float acc[TT];
            const float bb = s_b2[c];
            #pragma unroll
            for (int t = 0; t < TT; t++) acc[t] = bb;
            #pragma unroll
            for (int ci = 0; ci < CH; ci++) {
                #pragma unroll
                for (int k = 0; k < 5; k++) {
                    const float w = s_w2[(c*CH + ci)*5 + k];
                    const float* src = &s_y1[(ci*20 + f + k)*TS];
                    #pragma unroll
                    for (int t = 0; t < TT; t++) acc[t] = fmaf(w, src[t], acc[t]);
                }
            }
            if (gf < NF) {
                const size_t n = (size_t)b*NF + gf;
                #pragma unroll
                for (int t = 0; t < TT; t++) {
                    const int gt = t0 + t;
                    if (gt < NT) {
                        float v = acc[t];
                        v = (v >= 0.0f) ? v : a2*v;
                        xout[(n*NT + gt)*CH + c] = v;
                    }
                }
            }
        }
    }
}

// -------------------------------------------------------------------------
// Kernel 2: GRU (PyTorch gates) + FC + sigmoid.
// One wave per block; 2 sequences per wave; 32 lanes per sequence.
// Lane j owns hidden unit j; its 144 weights live in registers.
// NOTE: macro parameter renamed WT (a parameter named `w` would capture the
// `.w` member-access token of float4 during preprocessing).
// -------------------------------------------------------------------------
#define DOTX(acc, WT, q, v)                      \
    acc = fmaf(WT[4*(q)+0], (v).x, acc);         \
    acc = fmaf(WT[4*(q)+1], (v).y, acc);         \
    acc = fmaf(WT[4*(q)+2], (v).z, acc);         \
    acc = fmaf(WT[4*(q)+3], (v).w, acc)

__global__ __launch_bounds__(64) void gru_kernel(
    const float* __restrict__ xin,   // (NSEQ, NT, 16)
    const float* __restrict__ h0,    // (NSEQ, 32)
    const float* __restrict__ w_ih,  // (96, 16)
    const float* __restrict__ w_hh,  // (96, 32)
    const float* __restrict__ b_ih, const float* __restrict__ b_hh,
    const float* __restrict__ fc_w, const float* __restrict__ fc_b,
    float* __restrict__ prob,        // (NSEQ, NT)
    float* __restrict__ hout)        // (NSEQ, 32)
{
    __shared__ float s_h[2][HID];
    const int lane = threadIdx.x;
    const int g = lane >> 5;         // which of the 2 sequences
    const int j = lane & 31;         // hidden unit
    const size_t n = (size_t)blockIdx.x * 2 + g;   // NSEQ = 7696 is even

    float wir[16], wiz[16], win_[16];
    #pragma unroll
    for (int c = 0; c < 16; c++) {
        wir[c]  = w_ih[(      j)*16 + c];
        wiz[c]  = w_ih[(32 +  j)*16 + c];
        win_[c] = w_ih[(64 +  j)*16 + c];
    }
    float whr[32], whz[32], whn[32];
    #pragma unroll
    for (int k = 0; k < 32; k++) {
        whr[k] = w_hh[(      j)*32 + k];
        whz[k] = w_hh[(32 +  j)*32 + k];
        whn[k] = w_hh[(64 +  j)*32 + k];
    }
    const float bir = b_ih[j], biz = b_ih[32+j], bin_ = b_ih[64+j];
    const float bhr = b_hh[j], bhz = b_hh[32+j], bhn = b_hh[64+j];
    const float fcw = fc_w[j];
    const float fcb = fc_b[0];

    float h = h0[n*HID + j];
    s_h[g][j] = h;
    __syncthreads();

    const float4* xp = (const float4*)(xin + n*(size_t)NT*CH);
    float4 x0 = xp[0], x1 = xp[1], x2 = xp[2], x3 = xp[3];

    for (int t = 0; t < NT; t++) {
        // prefetch next step's x (independent of the h-chain)
        float4 p0, p1, p2, p3;
        if (t + 1 < NT) {
            p0 = xp[(t+1)*4+0]; p1 = xp[(t+1)*4+1];
            p2 = xp[(t+1)*4+2]; p3 = xp[(t+1)*4+3];
        } else {
            p0 = p1 = p2 = p3 = make_float4(0.f,0.f,0.f,0.f);
        }

        // x-projection: 3 dots of length 16
        float xr = bir, xz = biz, xn = bin_;
        DOTX(xr, wir, 0, x0); DOTX(xr, wir, 1, x1); DOTX(xr, wir, 2, x2); DOTX(xr, wir, 3, x3);
        DOTX(xz, wiz, 0, x0); DOTX(xz, wiz, 1, x1); DOTX(xz, wiz, 2, x2); DOTX(xz, wiz, 3, x3);
        DOTX(xn, win_,0, x0); DOTX(xn, win_,1, x1); DOTX(xn, win_,2, x2); DOTX(xn, win_,3, x3);

        // h-projection: 3 dots of length 32 (broadcast float4 reads from LDS)
        float hr = bhr, hz = bhz, hn = bhn;
        const float4* hp = (const float4*)s_h[g];
        #pragma unroll
        for (int q = 0; q < 8; q++) {
            const float4 hv = hp[q];
            DOTX(hr, whr, q, hv);
            DOTX(hz, whz, q, hv);
            DOTX(hn, whn, q, hv);
        }

        const float r  = sig_(xr + hr);
        const float z  = sig_(xz + hz);
        const float aa = xn + r*hn;
        const float nn = 2.0f*sig_(2.0f*aa) - 1.0f;   // tanh
        const float hnew = (1.0f - z)*nn + z*h;

        // FC + sigmoid: butterfly reduce within the 32-lane half
        float pacc = fcw * hnew;
        pacc += __shfl_xor(pacc, 1);
        pacc += __shfl_xor(pacc, 2);
        pacc += __shfl_xor(pacc, 4);
        pacc += __shfl_xor(pacc, 8);
        pacc += __shfl_xor(pacc, 16);
        if (j == 0) prob[n*(size_t)NT + t] = sig_(pacc + fcb);

        __syncthreads();          // all lanes done reading s_h
        s_h[g][j] = hnew;
        h = hnew;
        __syncthreads();          // new h visible

        x0 = p0; x1 = p1; x2 = p2; x3 = p3;
    }

    hout[n*HID + j] = h;
}

// -------------------------------------------------------------------------
extern "C" void kernel_launch(void* const* d_in, const int* in_sizes, int n_in,
                              void* d_out, int out_size, void* d_ws, size_t ws_size,
                              hipStream_t stream)
{
    const float* feat = (const float*)d_in[0];
    const float* h0   = (const float*)d_in[1];
    const float* w1   = (const float*)d_in[2];
    const float* b1   = (const float*)d_in[3];
    const float* a1   = (const float*)d_in[4];
    const float* w2   = (const float*)d_in[5];
    const float* b2   = (const float*)d_in[6];
    const float* a2   = (const float*)d_in[7];
    const float* wih  = (const float*)d_in[8];
    const float* whh  = (const float*)d_in[9];
    const float* bih  = (const float*)d_in[10];
    const float* bhh  = (const float*)d_in[11];
    const float* fcw  = (const float*)d_in[12];
    const float* fcb  = (const float*)d_in[13];

    float* xbuf = (float*)d_ws;                    // NSEQ*NT*16 floats = 246.3 MB
    float* prob = (float*)d_out;                   // (B, F, T) = NSEQ*NT
    float* hout = prob + (size_t)NSEQ*NT;          // (1, NSEQ, 32)

    dim3 cgrid(NB, (NF + FT - 1)/FT);              // (16, 31)
    conv_kernel<<<cgrid, 256, 0, stream>>>(feat, w1, b1, a1, w2, b2, a2, xbuf);
    gru_kernel<<<NSEQ/2, 64, 0, stream>>>(xbuf, h0, wih, whh, bih, bhh, fcw, fcb, prob, hout);
}